// Round 1
// baseline (138.006 us; speedup 1.0000x reference)
//
#include <hip/hip_runtime.h>
#include <math.h>

#define NF 512        // feature count
#define NP 118        // params per feature
#define FT 64         // features per block tile
#define ROWS 8        // rows per thread
#define ROWGROUPS 4
#define BLOCK_ROWS (ROWS * ROWGROUPS)  // 32 rows per block

__device__ __forceinline__ float fast_rcp(float x) {
    return __builtin_amdgcn_rcpf(x);
}

// tanh(x) = 1 - 2/(exp(2x)+1); saturates correctly at +/-inf overflow.
__device__ __forceinline__ float tanh_fast(float x) {
    float e = __expf(2.0f * x);
    return 1.0f - 2.0f * fast_rcp(e + 1.0f);
}

__device__ __forceinline__ float sigmoid_fast(float x) {
    return fast_rcp(1.0f + __expf(-x));
}

// Parameter class by flat index j in [0,118):
//  j<3 softplus(w L0), 3..5 copy(b), 6..8 tanh(s)
//  9..113: k=(j-9)%15 -> k<9 softplus(w), k<12 copy(b), else tanh(s)
//  114..116 softplus(w last), 117 copy(b last)
__device__ __forceinline__ float transform_one(float v, int j) {
    int cls;
    if (j < 3) cls = 0;
    else if (j < 6) cls = 1;
    else if (j < 9) cls = 2;
    else if (j < 114) { int k = (j - 9) % 15; cls = (k < 9) ? 0 : ((k < 12) ? 1 : 2); }
    else if (j < 117) cls = 0;
    else cls = 1;
    if (cls == 0) return fmaxf(v, 0.0f) + log1pf(expf(-fabsf(v)));  // stable softplus
    if (cls == 2) return tanhf(v);
    return v;
}

// Kernel 1: transform params once, store transposed t[j*NF + f].
__global__ void xform_kernel(const float* __restrict__ p, float* __restrict__ t) {
    int idx = blockIdx.x * 256 + threadIdx.x;
    if (idx >= NF * NP) return;
    int f = idx / NP;
    int j = idx - f * NP;
    t[j * NF + f] = transform_one(p[idx], j);
}

// Main kernel: each thread = one feature column, ROWS rows.
template <bool FUSE_XFORM>
__global__ __launch_bounds__(256)
void cdf_kernel(const float* __restrict__ x, const float* __restrict__ prm,
                float* __restrict__ out) {
    __shared__ float lds[NP * FT];   // layout [j][FT] -> conflict-free lane reads
    const int tid = threadIdx.x;
    const int fi  = tid & (FT - 1);
    const int rg  = tid >> 6;
    const int f0  = blockIdx.x * FT;
    const int b0  = blockIdx.y * BLOCK_ROWS + rg * ROWS;
    const int f   = f0 + fi;

    if constexpr (FUSE_XFORM) {
        // raw params layout [f][NP]; transform while staging
        for (int idx = tid; idx < FT * NP; idx += 256) {
            int fl = idx / NP;
            int j  = idx - fl * NP;
            lds[j * FT + fl] = transform_one(prm[(f0 + fl) * NP + j], j);
        }
    } else {
        // pre-transformed transposed layout [j][NF]; coalesced stage
        for (int idx = tid; idx < NP * FT; idx += 256) {
            int j  = idx >> 6;
            int fl = idx & (FT - 1);
            lds[idx] = prm[j * NF + f0 + fl];
        }
    }

    float xin[ROWS];
#pragma unroll
    for (int r = 0; r < ROWS; ++r)
        xin[r] = x[(b0 + r) * NF + f];

    __syncthreads();

    const float* Lp = lds + fi;
#define PRM(J) Lp[(J) * FT]

    float h0[ROWS], h1[ROWS], h2[ROWS];
    // layer 0: w (3,1), b, s
    {
        const float w0 = PRM(0), w1 = PRM(1), w2 = PRM(2);
        const float c0 = PRM(3), c1 = PRM(4), c2 = PRM(5);
        const float s0 = PRM(6), s1 = PRM(7), s2 = PRM(8);
#pragma unroll
        for (int r = 0; r < ROWS; ++r) {
            float a0 = fmaf(xin[r], w0, c0);
            float a1 = fmaf(xin[r], w1, c1);
            float a2 = fmaf(xin[r], w2, c2);
            h0[r] = fmaf(s0, tanh_fast(a0), a0);
            h1[r] = fmaf(s1, tanh_fast(a1), a1);
            h2[r] = fmaf(s2, tanh_fast(a2), a2);
        }
    }
    // middle layers 1..7: w (3,3) row-major, b, s
#pragma unroll
    for (int li = 1; li < 8; ++li) {
        const int base = 9 + 15 * (li - 1);
        const float w00 = PRM(base + 0), w01 = PRM(base + 1), w02 = PRM(base + 2);
        const float w10 = PRM(base + 3), w11 = PRM(base + 4), w12 = PRM(base + 5);
        const float w20 = PRM(base + 6), w21 = PRM(base + 7), w22 = PRM(base + 8);
        const float c0  = PRM(base + 9), c1  = PRM(base + 10), c2 = PRM(base + 11);
        const float s0  = PRM(base + 12), s1 = PRM(base + 13), s2 = PRM(base + 14);
#pragma unroll
        for (int r = 0; r < ROWS; ++r) {
            float a0 = fmaf(h0[r], w00, fmaf(h1[r], w01, fmaf(h2[r], w02, c0)));
            float a1 = fmaf(h0[r], w10, fmaf(h1[r], w11, fmaf(h2[r], w12, c1)));
            float a2 = fmaf(h0[r], w20, fmaf(h1[r], w21, fmaf(h2[r], w22, c2)));
            h0[r] = fmaf(s0, tanh_fast(a0), a0);
            h1[r] = fmaf(s1, tanh_fast(a1), a1);
            h2[r] = fmaf(s2, tanh_fast(a2), a2);
        }
    }
    // final layer: w (1,3), b, sigmoid
    {
        const float w0 = PRM(114), w1 = PRM(115), w2 = PRM(116), cb = PRM(117);
#pragma unroll
        for (int r = 0; r < ROWS; ++r) {
            float a = fmaf(h0[r], w0, fmaf(h1[r], w1, fmaf(h2[r], w2, cb)));
            out[(b0 + r) * NF + f] = sigmoid_fast(a);
        }
    }
#undef PRM
}

extern "C" void kernel_launch(void* const* d_in, const int* in_sizes, int n_in,
                              void* d_out, int out_size, void* d_ws, size_t ws_size,
                              hipStream_t stream) {
    const float* x = (const float*)d_in[0];       // (B, 512) f32
    const float* p = (const float*)d_in[1];       // (512, 118) f32
    float* out = (float*)d_out;                   // (B, 512) f32

    const int B = in_sizes[0] / NF;               // 32768
    dim3 grid(NF / FT, B / BLOCK_ROWS);           // (8, 1024)
    dim3 block(256);

    if (ws_size >= (size_t)(NF * NP * sizeof(float))) {
        float* t = (float*)d_ws;
        xform_kernel<<<(NF * NP + 255) / 256, 256, 0, stream>>>(p, t);
        cdf_kernel<false><<<grid, block, 0, stream>>>(x, t, out);
    } else {
        cdf_kernel<true><<<grid, block, 0, stream>>>(x, p, out);
    }
}